// Round 7
// baseline (108.289 us; speedup 1.0000x reference)
//
#include <hip/hip_runtime.h>

#define NBINS 100
#define NROWS 101          // row 100 = spill slot for x -> 1.0 boundary (discarded)
#define BLK   64           // one wave per block; column == lane (exclusive)
#define GRID  1536         // 6 blocks/CU (LDS ~25.9 KB/block)
#define REP   8            // global accumulator replicas (atomic contention relief)

typedef unsigned int       u32;
typedef unsigned long long u64;
typedef float f32x4 __attribute__((ext_vector_type(4)));

// Per-element: u = round(x*102400) -> k = u>>10 (bin), ti = u&1023 (frac in 1/1024).
// Column cell (u32): (N << 20) + sum(ti).  Per-lane <=~683 elems -> T < 2^20.
// Global cell (u64): (N << 37) + T_total.  Exact integer accumulation.
// count[b] = 0.01 * (N_b + (T_{b-1} - T_b)/1024);  out = count / (sum + 1e-6).
// g[REP*NBINS] is the block-completion ticket counter (last block finalizes).

__global__ void histo_zero(u64* __restrict__ g) {
    int i = blockIdx.x * blockDim.x + threadIdx.x;
    if (i < REP * NBINS + 1) g[i] = 0ull;
}

__global__ __launch_bounds__(BLK) void histo_accum(const float* __restrict__ x,
                                                   u64* __restrict__ g,
                                                   float* __restrict__ out,
                                                   int n4, int n, int nblocks) {
    __shared__ u32   h[NROWS * BLK];
    __shared__ float Tsh[NBINS + 1];
    __shared__ int   lastFlag;
    const int lane = threadIdx.x;

    for (int i = lane; i < NROWS * BLK; i += BLK) h[i] = 0u;
    __syncthreads();

// Two elements per batch: both reads issue before either write (one LDS round
// trip per 2 elements). Same-bin collision merged in registers beforehand.
#define PROC2(va, vb) {                                        \
        u32 u0 = (u32)((va) * 102400.0f + 0.5f);               \
        u32 u1 = (u32)((vb) * 102400.0f + 0.5f);               \
        u32 k0 = u0 >> 10, k1 = u1 >> 10;                      \
        u32 w0 = (1u << 20) + (u0 & 1023u);                    \
        u32 w1 = (1u << 20) + (u1 & 1023u);                    \
        bool eq = (k0 == k1);                                  \
        u32 w1m = w1 + (eq ? w0 : 0u);                         \
        u32 w0m = eq ? 0u : w0;                                \
        int a0 = (int)(k0 * BLK) + lane;                       \
        int a1 = (int)(k1 * BLK) + lane;                       \
        u32 d0 = h[a0];                                        \
        u32 d1 = h[a1];                                        \
        h[a0] = d0 + w0m;                                      \
        h[a1] = d1 + w1m;                                      \
    }

#define PROC1(va) {                                            \
        u32 u0 = (u32)((va) * 102400.0f + 0.5f);               \
        u32 k0 = u0 >> 10;                                     \
        int a0 = (int)(k0 * BLK) + lane;                       \
        h[a0] += (1u << 20) + (u0 & 1023u);                    \
    }

#define PROC2x2(v) { PROC2((v).x, (v).y); PROC2((v).z, (v).w); }

#define LD8(Bk, p) {                                           \
        Bk##0 = __builtin_nontemporal_load((p));               \
        Bk##1 = __builtin_nontemporal_load((p) + 1 * stride);  \
        Bk##2 = __builtin_nontemporal_load((p) + 2 * stride);  \
        Bk##3 = __builtin_nontemporal_load((p) + 3 * stride);  \
        Bk##4 = __builtin_nontemporal_load((p) + 4 * stride);  \
        Bk##5 = __builtin_nontemporal_load((p) + 5 * stride);  \
        Bk##6 = __builtin_nontemporal_load((p) + 6 * stride);  \
        Bk##7 = __builtin_nontemporal_load((p) + 7 * stride);  \
    }

#define PR8(Bk) { PROC2x2(Bk##0); PROC2x2(Bk##1); PROC2x2(Bk##2); PROC2x2(Bk##3); \
                  PROC2x2(Bk##4); PROC2x2(Bk##5); PROC2x2(Bk##6); PROC2x2(Bk##7); }

    const f32x4* __restrict__ x4 = (const f32x4*)x;
    const int stride = gridDim.x * BLK;
    const int base   = blockIdx.x * BLK + lane;

    // Software-pipelined main loop: bank B loads (group g+1) issue BEFORE
    // bank A (group g) is processed -> 8 loads stay in flight during the
    // ~1100-cyc LDS chain phase. Static bank names (no runtime indexing).
    const int nfull = n4 / (8 * stride);
    const f32x4* p  = x4 + base;

    if (nfull >= 1) {
        f32x4 A0, A1, A2, A3, A4, A5, A6, A7;
        f32x4 B0, B1, B2, B3, B4, B5, B6, B7;
        LD8(A, p); p += 8 * stride;
        int grp = 1;
        for (; grp + 1 < nfull; grp += 2) {
            LD8(B, p); p += 8 * stride;
            PR8(A);
            LD8(A, p); p += 8 * stride;
            PR8(B);
        }
        if (grp < nfull) {
            LD8(B, p); p += 8 * stride;
            PR8(A);
            PR8(B);
        } else {
            PR8(A);
        }
    }
    // ragged remainder (grid-stride indices past the full groups)
    for (int j = nfull * 8; base + j * stride < n4; ++j) {
        f32x4 v = __builtin_nontemporal_load(x4 + base + j * stride);
        PROC2x2(v);
    }
    // scalar tail (n % 4) — block 0 only
    if (blockIdx.x == 0) {
        for (int t = n4 * 4 + lane; t < n; t += BLK) { float v = x[t]; PROC1(v); }
    }
#undef PR8
#undef LD8
#undef PROC2x2
#undef PROC1
#undef PROC2

    __syncthreads();

    // Reduce 64 columns/bin (diagonal sweep: bank = (c+lane)%32, 2-way = free),
    // one packed-u64 global atomic per bin per block (8 replicas).
    u64* grep = &g[(blockIdx.x & (REP - 1)) * NBINS];
    for (int b = lane; b < NBINS; b += BLK) {
        u32 Ns = 0, Ts = 0;
#pragma unroll
        for (int c = 0; c < BLK; ++c) {
            int cc = (c + lane) & (BLK - 1);
            u32 u = h[b * BLK + cc];
            Ns += u >> 20;
            Ts += u & 0xFFFFFu;
        }
        atomicAdd(&grep[b], ((u64)Ns << 37) + (u64)Ts);
    }

    // ---- fused finalize: last block to arrive normalizes and writes out ----
    __threadfence();
    if (lane == 0) {
        u64 done = atomicAdd(&g[REP * NBINS], 1ull);
        lastFlag = (done == (u64)(nblocks - 1));
    }
    __syncthreads();
    if (!lastFlag) return;
    __threadfence();

    // Read accumulators via atomic RMW (coherent point; safe across XCD L2s).
    u64 a0 = 0ull, a1 = 0ull;
#pragma unroll
    for (int r = 0; r < REP; ++r) {
        a0 += atomicAdd(&g[r * NBINS + lane], 0ull);
        if (lane + 64 < NBINS) a1 += atomicAdd(&g[r * NBINS + lane + 64], 0ull);
    }
    float N0 = (float)(a0 >> 37), T0 = (float)(a0 & ((1ull << 37) - 1ull));
    float N1 = (float)(a1 >> 37), T1 = (float)(a1 & ((1ull << 37) - 1ull));

    Tsh[lane + 1] = T0;
    if (lane + 64 < NBINS) Tsh[lane + 65] = T1;
    if (lane == 0) Tsh[0] = 0.0f;
    __syncthreads();

    float c0 = 0.01f * (N0 + (Tsh[lane] - T0) * (1.0f / 1024.0f));
    float c1 = (lane + 64 < NBINS)
             ? 0.01f * (N1 + (Tsh[lane + 64] - T1) * (1.0f / 1024.0f)) : 0.0f;

    float s = c0 + c1;
#pragma unroll
    for (int o = 32; o > 0; o >>= 1) s += __shfl_down(s, o, 64);
    s = __shfl(s, 0, 64);

    out[lane] = c0 / (s + 1e-6f);
    if (lane + 64 < NBINS) out[lane + 64] = c1 / (s + 1e-6f);
}

extern "C" void kernel_launch(void* const* d_in, const int* in_sizes, int n_in,
                              void* d_out, int out_size, void* d_ws, size_t ws_size,
                              hipStream_t stream) {
    const float* x   = (const float*)d_in[0];  // [64 * 1048576] fp32 in [0,1)
    float*       out = (float*)d_out;          // [100] fp32
    u64*         g   = (u64*)d_ws;             // REP*100 u64 + 1 ticket counter

    const int n  = in_sizes[0];
    const int n4 = n / 4;

    histo_zero<<<(REP * NBINS + 1 + 255) / 256, 256, 0, stream>>>(g);

    int blocks = GRID;
    int need   = (n4 + BLK - 1) / BLK;
    if (blocks > need) blocks = need;
    histo_accum<<<blocks, BLK, 0, stream>>>(x, g, out, n4, n, blocks);
}

// Round 8
// 85.504 us; speedup vs baseline: 1.2665x; 1.2665x over previous
//
#include <hip/hip_runtime.h>

#define NBINS 100
#define NROWS 101          // row 100 = spill slot for x -> 1.0 boundary (discarded)
#define BLK   64           // one wave per block; column == lane (exclusive)
#define GRID  1536         // 6 blocks/CU (LDS ~25.9 KB/block)
#define REP   8            // global accumulator replicas (atomic contention relief)

typedef unsigned int       u32;
typedef unsigned long long u64;

// Per-element: u = round(x*102400) -> k = u>>10 (bin), ti = u&1023 (frac 1/1024).
// Column cell (u32): (N << 20) + sum(ti).  Per-lane <=683 elems -> T < 2^20.
// Global cell (u64): (N << 37) + T_total.  Exact integer accumulation.
// count[b] = 0.01 * (N_b + (T_{b-1} - T_b)/1024);  out = count / (sum + 1e-6).
// g[REP*NBINS] is the block-completion ticket (last block finalizes).

__global__ void histo_zero(u64* __restrict__ g) {
    int i = blockIdx.x * blockDim.x + threadIdx.x;
    if (i < REP * NBINS + 1) g[i] = 0ull;
}

__global__ __launch_bounds__(BLK) void histo_accum(const float* __restrict__ x,
                                                   u64* __restrict__ g,
                                                   float* __restrict__ out,
                                                   int n4, int n, int nblocks) {
    __shared__ u32   h[NROWS * BLK];
    __shared__ float Tsh[NBINS + 1];
    __shared__ int   lastFlag;
    const int lane = threadIdx.x;

    for (int i = lane; i < NROWS * BLK; i += BLK) h[i] = 0u;
    __syncthreads();

// Two elements per batch: both reads issue before either write (one LDS round
// trip per 2 elements). Same-bin collision merged in registers beforehand so
// "last write wins" is correct (both reads see the same stale base).
#define PROC2(va, vb) {                                        \
        u32 u0 = (u32)((va) * 102400.0f + 0.5f);               \
        u32 u1 = (u32)((vb) * 102400.0f + 0.5f);               \
        u32 k0 = u0 >> 10, k1 = u1 >> 10;                      \
        u32 w0 = (1u << 20) + (u0 & 1023u);                    \
        u32 w1 = (1u << 20) + (u1 & 1023u);                    \
        bool eq = (k0 == k1);                                  \
        u32 w1m = w1 + (eq ? w0 : 0u);                         \
        u32 w0m = eq ? 0u : w0;                                \
        int a0 = (int)(k0 * BLK) + lane;                       \
        int a1 = (int)(k1 * BLK) + lane;                       \
        u32 d0 = h[a0];                                        \
        u32 d1 = h[a1];                                        \
        h[a0] = d0 + w0m;                                      \
        h[a1] = d1 + w1m;                                      \
    }

#define PROC1(va) {                                            \
        u32 u0 = (u32)((va) * 102400.0f + 0.5f);               \
        u32 k0 = u0 >> 10;                                     \
        int a0 = (int)(k0 * BLK) + lane;                       \
        h[a0] += (1u << 20) + (u0 & 1023u);                    \
    }

#define PROC2x2(v) { PROC2((v).x, (v).y); PROC2((v).z, (v).w); }

    const float4* __restrict__ x4 = (const float4*)x;
    const int stride = gridDim.x * BLK;
    int i = blockIdx.x * BLK + lane;

    // 8 float4 loads in flight per lane (128 B) — HBM latency amortized over
    // 16 LDS-chain batches per iteration. (R6-proven loop, untouched.)
    for (; i + 7 * stride < n4; i += 8 * stride) {
        float4 v0 = x4[i];
        float4 v1 = x4[i + 1 * stride];
        float4 v2 = x4[i + 2 * stride];
        float4 v3 = x4[i + 3 * stride];
        float4 v4 = x4[i + 4 * stride];
        float4 v5 = x4[i + 5 * stride];
        float4 v6 = x4[i + 6 * stride];
        float4 v7 = x4[i + 7 * stride];
        PROC2x2(v0); PROC2x2(v1); PROC2x2(v2); PROC2x2(v3);
        PROC2x2(v4); PROC2x2(v5); PROC2x2(v6); PROC2x2(v7);
    }
    for (; i < n4; i += stride) {
        float4 v = x4[i];
        PROC2x2(v);
    }
    if (blockIdx.x == 0) {               // scalar tail (n % 4)
        for (int t = n4 * 4 + lane; t < n; t += BLK) { float v = x[t]; PROC1(v); }
    }
#undef PROC2x2
#undef PROC1
#undef PROC2

    __syncthreads();

    // Reduce 64 columns/bin (diagonal sweep: bank = (c+lane)%32, 2-way = free),
    // one packed-u64 global atomic per bin per block (8 replicas).
    u64* grep = &g[(blockIdx.x & (REP - 1)) * NBINS];
    for (int b = lane; b < NBINS; b += BLK) {
        u32 Ns = 0, Ts = 0;
#pragma unroll
        for (int c = 0; c < BLK; ++c) {
            int cc = (c + lane) & (BLK - 1);
            u32 u = h[b * BLK + cc];
            Ns += u >> 20;
            Ts += u & 0xFFFFFu;
        }
        atomicAdd(&grep[b], ((u64)Ns << 37) + (u64)Ts);
    }

    // ---- fused finalize: last block to finish normalizes and writes out ----
    __threadfence();
    if (lane == 0) {
        u64 done = atomicAdd(&g[REP * NBINS], 1ull);
        lastFlag = (done == (u64)(nblocks - 1));
    }
    __syncthreads();
    if (!lastFlag) return;
    __threadfence();

    // Read accumulators at the coherent point (atomic RMW) — safe across XCDs.
    u64 a0 = 0ull, a1 = 0ull;
#pragma unroll
    for (int r = 0; r < REP; ++r) {
        a0 += atomicAdd(&g[r * NBINS + lane], 0ull);
        if (lane + 64 < NBINS) a1 += atomicAdd(&g[r * NBINS + lane + 64], 0ull);
    }
    float N0 = (float)(a0 >> 37), T0 = (float)(a0 & ((1ull << 37) - 1ull));
    float N1 = (float)(a1 >> 37), T1 = (float)(a1 & ((1ull << 37) - 1ull));

    Tsh[lane + 1] = T0;
    if (lane + 64 < NBINS) Tsh[lane + 65] = T1;
    if (lane == 0) Tsh[0] = 0.0f;
    __syncthreads();

    float c0 = 0.01f * (N0 + (Tsh[lane] - T0) * (1.0f / 1024.0f));
    float c1 = (lane + 64 < NBINS)
             ? 0.01f * (N1 + (Tsh[lane + 64] - T1) * (1.0f / 1024.0f)) : 0.0f;

    float s = c0 + c1;
#pragma unroll
    for (int o = 32; o > 0; o >>= 1) s += __shfl_down(s, o, 64);
    s = __shfl(s, 0, 64);

    out[lane] = c0 / (s + 1e-6f);
    if (lane + 64 < NBINS) out[lane + 64] = c1 / (s + 1e-6f);
}

extern "C" void kernel_launch(void* const* d_in, const int* in_sizes, int n_in,
                              void* d_out, int out_size, void* d_ws, size_t ws_size,
                              hipStream_t stream) {
    const float* x   = (const float*)d_in[0];  // [64 * 1048576] fp32 in [0,1)
    float*       out = (float*)d_out;          // [100] fp32
    u64*         g   = (u64*)d_ws;             // REP*100 u64 + 1 ticket counter

    const int n  = in_sizes[0];
    const int n4 = n / 4;

    histo_zero<<<(REP * NBINS + 1 + 255) / 256, 256, 0, stream>>>(g);

    int blocks = GRID;
    int need   = (n4 + BLK - 1) / BLK;
    if (blocks > need) blocks = need;
    histo_accum<<<blocks, BLK, 0, stream>>>(x, g, out, n4, n, blocks);
}

// Round 9
// 59.760 us; speedup vs baseline: 1.8120x; 1.4308x over previous
//
#include <hip/hip_runtime.h>

#define NBINS 100
#define NROWS 101          // row 100 = spill slot for x -> 1.0 boundary (discarded)
#define BLK   64           // one wave per block; column == lane (exclusive)
#define GRID  1536         // 6 blocks/CU (LDS ~25.9 KB/block)
#define REP   8            // global accumulator replicas (atomic contention relief)

typedef unsigned int       u32;
typedef unsigned long long u64;

// Per-element: u = round(x*102400) -> k = u>>10 (bin), ti = u&1023 (frac 1/1024).
// Column cell (u32): (N << 20) + sum(ti).  Per-lane <=683 elems -> T < 2^20.
// Global cell (u64): (N << 37) + T_total.  Exact integer accumulation.
// count[b] = 0.01 * (N_b + (T_{b-1} - T_b)/1024);  out = count / (sum + 1e-6).

__global__ void histo_zero(u64* __restrict__ g) {
    int i = blockIdx.x * blockDim.x + threadIdx.x;
    if (i < REP * NBINS) g[i] = 0ull;
}

__global__ __launch_bounds__(BLK) void histo_accum(const float* __restrict__ x,
                                                   u64* __restrict__ g,
                                                   int n4, int n) {
    __shared__ u32 h[NROWS * BLK];
    const int lane = threadIdx.x;

    for (int i = lane; i < NROWS * BLK; i += BLK) h[i] = 0u;
    __syncthreads();

// Two elements per batch: both reads issue before either write (one LDS round
// trip per 2 elements). Same-bin collision merged in registers beforehand so
// "last write wins" is correct (both reads see the same stale base).
#define PROC2(va, vb) {                                        \
        u32 u0 = (u32)((va) * 102400.0f + 0.5f);               \
        u32 u1 = (u32)((vb) * 102400.0f + 0.5f);               \
        u32 k0 = u0 >> 10, k1 = u1 >> 10;                      \
        u32 w0 = (1u << 20) + (u0 & 1023u);                    \
        u32 w1 = (1u << 20) + (u1 & 1023u);                    \
        bool eq = (k0 == k1);                                  \
        u32 w1m = w1 + (eq ? w0 : 0u);                         \
        u32 w0m = eq ? 0u : w0;                                \
        int a0 = (int)(k0 * BLK) + lane;                       \
        int a1 = (int)(k1 * BLK) + lane;                       \
        u32 d0 = h[a0];                                        \
        u32 d1 = h[a1];                                        \
        h[a0] = d0 + w0m;                                      \
        h[a1] = d1 + w1m;                                      \
    }

#define PROC1(va) {                                            \
        u32 u0 = (u32)((va) * 102400.0f + 0.5f);               \
        u32 k0 = u0 >> 10;                                     \
        int a0 = (int)(k0 * BLK) + lane;                       \
        h[a0] += (1u << 20) + (u0 & 1023u);                    \
    }

#define PROC2x2(v) { PROC2((v).x, (v).y); PROC2((v).z, (v).w); }

// Plain cached loads, R6 index addressing. Bk##0..7 are static names (rule #20).
#define LD8(Bk, ii) {                                          \
        Bk##0 = x4[(ii)];                                      \
        Bk##1 = x4[(ii) + 1 * stride];                         \
        Bk##2 = x4[(ii) + 2 * stride];                         \
        Bk##3 = x4[(ii) + 3 * stride];                         \
        Bk##4 = x4[(ii) + 4 * stride];                         \
        Bk##5 = x4[(ii) + 5 * stride];                         \
        Bk##6 = x4[(ii) + 6 * stride];                         \
        Bk##7 = x4[(ii) + 7 * stride];                         \
    }

#define PR8(Bk) { PROC2x2(Bk##0); PROC2x2(Bk##1); PROC2x2(Bk##2); PROC2x2(Bk##3); \
                  PROC2x2(Bk##4); PROC2x2(Bk##5); PROC2x2(Bk##6); PROC2x2(Bk##7); }

    const float4* __restrict__ x4 = (const float4*)x;
    const int stride = gridDim.x * BLK;
    int i = blockIdx.x * BLK + lane;

    // Software pipeline, 1 group deep: loads for group g+1 are issued BEFORE
    // group g's LDS chain; sched_barrier(0) pins them above the chain so each
    // wave keeps 8 loads outstanding during the ~1500-cyc RMW phase (R6's
    // sawtooth averaged only ~2.8 -> 5.36 TB/s; this should reach ~6.5).
    int cnt = 0;
    if (n4 - i > 7 * stride) cnt = (n4 - i - 7 * stride + 8 * stride - 1) / (8 * stride);

    if (cnt > 0) {
        float4 A0, A1, A2, A3, A4, A5, A6, A7;
        float4 B0, B1, B2, B3, B4, B5, B6, B7;
        LD8(A, i); i += 8 * stride; cnt--;
        while (cnt >= 2) {
            LD8(B, i); i += 8 * stride;
            __builtin_amdgcn_sched_barrier(0);
            PR8(A);
            LD8(A, i); i += 8 * stride;
            __builtin_amdgcn_sched_barrier(0);
            PR8(B);
            cnt -= 2;
        }
        if (cnt == 1) {
            LD8(B, i); i += 8 * stride;
            __builtin_amdgcn_sched_barrier(0);
            PR8(A);
            PR8(B);
        } else {
            PR8(A);
        }
    }
    for (; i < n4; i += stride) {        // ragged remainder
        float4 v = x4[i];
        PROC2x2(v);
    }
    if (blockIdx.x == 0) {               // scalar tail (n % 4)
        for (int t = n4 * 4 + lane; t < n; t += BLK) { float v = x[t]; PROC1(v); }
    }
#undef PR8
#undef LD8
#undef PROC2x2
#undef PROC1
#undef PROC2

    __syncthreads();

    // Reduce 64 columns/bin (diagonal sweep: bank = (c+lane)%32, 2-way = free),
    // one packed-u64 global atomic per bin per block (8 replicas).
    u64* grep = &g[(blockIdx.x & (REP - 1)) * NBINS];
    for (int b = lane; b < NBINS; b += BLK) {
        u32 Ns = 0, Ts = 0;
#pragma unroll
        for (int c = 0; c < BLK; ++c) {
            int cc = (c + lane) & (BLK - 1);
            u32 u = h[b * BLK + cc];
            Ns += u >> 20;
            Ts += u & 0xFFFFFu;
        }
        atomicAdd(&grep[b], ((u64)Ns << 37) + (u64)Ts);
    }
}

__global__ void histo_final(const u64* __restrict__ g, float* __restrict__ out) {
    __shared__ float Tprev[NBINS + 1];
    __shared__ float wsum[2];
    const int t = threadIdx.x;           // 128 threads = 2 waves

    float N = 0.0f, T = 0.0f;
    if (t < NBINS) {
        u64 acc = 0ull;
#pragma unroll
        for (int r = 0; r < REP; ++r) acc += g[r * NBINS + t];
        N = (float)(acc >> 37);
        T = (float)(acc & ((1ull << 37) - 1ull));
        Tprev[t + 1] = T;
    }
    if (t == 127) Tprev[0] = 0.0f;
    __syncthreads();

    float c = 0.0f;
    if (t < NBINS) c = 0.01f * (N + (Tprev[t] - T) * (1.0f / 1024.0f));

    float s = c;
#pragma unroll
    for (int o = 32; o > 0; o >>= 1) s += __shfl_down(s, o, 64);
    if ((t & 63) == 0) wsum[t >> 6] = s;
    __syncthreads();

    float total = wsum[0] + wsum[1];
    if (t < NBINS) out[t] = c / (total + 1e-6f);
}

extern "C" void kernel_launch(void* const* d_in, const int* in_sizes, int n_in,
                              void* d_out, int out_size, void* d_ws, size_t ws_size,
                              hipStream_t stream) {
    const float* x   = (const float*)d_in[0];  // [64 * 1048576] fp32 in [0,1)
    float*       out = (float*)d_out;          // [100] fp32
    u64*         g   = (u64*)d_ws;             // REP*100 u64 accumulators

    const int n  = in_sizes[0];
    const int n4 = n / 4;

    histo_zero<<<(REP * NBINS + 255) / 256, 256, 0, stream>>>(g);

    int blocks = GRID;
    int need   = (n4 + BLK - 1) / BLK;
    if (blocks > need) blocks = need;
    histo_accum<<<blocks, BLK, 0, stream>>>(x, g, n4, n);

    histo_final<<<1, 128, 0, stream>>>(g, out);
}